// Round 1
// baseline (649.164 us; speedup 1.0000x reference)
//
#include <hip/hip_runtime.h>
#include <math.h>

#define T_FIRE 3000
#define B_SZ 16
#define C_CH 32
#define HID 128
#define NF 128
#define H_SW 32
#define W_SW 375
#define DSW 192
#define DM 512
#define P_POLY 32
#define DP 32

// ---------------- K1: alpha = softplus(proj(relu(dense(LN(conv+res))))) ----
// one wave (64 lanes) per (b,t) row; lanes 0..31 and 32..63 both hold channel
// c = lane&31 (duplicate halves make the 64-lane reductions give 2*sum32).
__global__ __launch_bounds__(256) void alpha_kernel(
    const float* __restrict__ fs, const float* __restrict__ conv_w,
    const float* __restrict__ ln_w, const float* __restrict__ ln_b,
    const float* __restrict__ dense_w, const float* __restrict__ dense_b,
    const float* __restrict__ proj_w, const float* __restrict__ proj_b,
    float* __restrict__ alpha_out)
{
    int lane = threadIdx.x & 63;
    int wave = threadIdx.x >> 6;
    int r = blockIdx.x * 4 + wave;            // < 48000 always
    int b = r / T_FIRE, t = r - b * T_FIRE;
    int c = lane & 31;
    long base = ((long)(b * T_FIRE + t)) * C_CH + c;
    float xc = fs[base];
    float xm = (t > 0)          ? fs[base - C_CH] : 0.f;
    float xp = (t < T_FIRE - 1) ? fs[base + C_CH] : 0.f;
    float w0 = conv_w[c * 3 + 0], w1 = conv_w[c * 3 + 1], w2 = conv_w[c * 3 + 2];
    // cross-correlation (lax conv) + residual
    float x = xc + xm * w0 + xc * w1 + xp * w2;
    // LayerNorm over C=32 (biased var)
    float s = x, s2 = x * x;
#pragma unroll
    for (int o = 1; o < 64; o <<= 1) { s += __shfl_xor(s, o); s2 += __shfl_xor(s2, o); }
    float mean = s * (1.f / 64.f);
    float var  = s2 * (1.f / 64.f) - mean * mean;
    float xn = (x - mean) * rsqrtf(var + 1e-5f) * ln_w[c] + ln_b[c];
    // dense [32->128]: lane computes hidden units lane and lane+64
    float a0 = dense_b[lane], a1 = dense_b[lane + 64];
#pragma unroll
    for (int cc = 0; cc < 32; cc++) {
        float xv = __shfl(xn, cc);
        a0 = fmaf(xv, dense_w[cc * HID + lane], a0);
        a1 = fmaf(xv, dense_w[cc * HID + lane + 64], a1);
    }
    a0 = fmaxf(a0, 0.f);
    a1 = fmaxf(a1, 0.f);
    float v = a0 * proj_w[lane] + a1 * proj_w[lane + 64];
#pragma unroll
    for (int o = 1; o < 64; o <<= 1) v += __shfl_xor(v, o);
    if (lane == 0) {
        float z = v + proj_b[0];
        alpha_out[r] = fmaxf(z, 0.f) + log1pf(expf(-fabsf(z)));  // softplus
    }
}

// ---------------- K2: fires scan + qty partials -----------------------------
// one block (1024 thr) per batch. Ordered rank of each fire via ballot +
// prefix popcount + cross-wave scan. fire_w[b][rank] = idx>>3 (== idx*375/3000).
__global__ __launch_bounds__(1024) void fires_kernel(
    const float* __restrict__ alpha, const int* __restrict__ target,
    int* __restrict__ fw, float* __restrict__ qpart)
{
    __shared__ int wtot[16];
    __shared__ int sbase;
    __shared__ float ssig[16];
    int b = blockIdx.x, tid = threadIdx.x;
    int lane = tid & 63, w = tid >> 6;
    if (tid < NF) fw[b * NF + tid] = (T_FIRE - 1) >> 3;   // 374 = padded slots
    if (tid == 0) sbase = 0;
    float psig = 0.f;
    __syncthreads();
    for (int chunk = 0; chunk < 3; chunk++) {
        int idx = chunk * 1024 + tid;
        bool valid = idx < T_FIRE;
        float a = valid ? alpha[b * T_FIRE + idx] : 0.f;
        if (valid) psig += 1.f / (1.f + expf(-(a - 1.0f) * 10.f));
        bool flag = valid && (a > 1.0f);
        unsigned long long mask = __ballot(flag);
        int prefix = __popcll(mask & ((1ull << lane) - 1ull));
        if (lane == 0) wtot[w] = __popcll(mask);
        __syncthreads();
        if (tid == 0) {
            int run = sbase;
            for (int i = 0; i < 16; i++) { int v2 = wtot[i]; wtot[i] = run; run += v2; }
            sbase = run;
        }
        __syncthreads();
        int rank = wtot[w] + prefix;
        if (flag && rank < NF) fw[b * NF + rank] = idx >> 3;
        __syncthreads();
    }
#pragma unroll
    for (int o = 1; o < 64; o <<= 1) psig += __shfl_xor(psig, o);
    if (lane == 0) ssig[w] = psig;
    __syncthreads();
    if (tid == 0) {
        float tot = 0.f;
        for (int i = 0; i < 16; i++) tot += ssig[i];
        qpart[b] = fabsf(tot - (float)target[b]);
    }
}

// ---------------- K3: qty_loss = mean(qpart) --------------------------------
__global__ void qty_kernel(const float* __restrict__ qpart, float* __restrict__ out)
{
    int lane = threadIdx.x;
    float v = (lane < B_SZ) ? qpart[lane] : 0.f;
#pragma unroll
    for (int o = 1; o < 64; o <<= 1) v += __shfl_xor(v, o);
    if (lane == 0) out[0] = v * (1.f / B_SZ);
}

// ---------------- K4: pitch_tok = pitch_tokens @ pitch_w + pitch_b ----------
// block = one (b,n) x 256-col slab; 256 thr; thread tile 4 rows x 8 cols.
__global__ __launch_bounds__(256) void pitch_kernel(
    const float* __restrict__ pt, const float* __restrict__ pw,
    const float* __restrict__ pb, float* __restrict__ acoustic)
{
    __shared__ float As[P_POLY * DP];     // 32x32
    __shared__ float Bs[DP][256];         // 32x256
    int bid = blockIdx.x;
    int slab = bid & 1;
    int bn = bid >> 1;
    int tid = threadIdx.x;
    // stage A (1024 floats = 256 float4)
    ((float4*)As)[tid] = ((const float4*)(pt + (long)bn * (P_POLY * DP)))[tid];
    // stage B slab (32x256 = 2048 float4, 8/thread)
#pragma unroll
    for (int i = 0; i < 8; i++) {
        int idx = tid + i * 256;
        int kr = idx >> 6, c4 = idx & 63;
        *(float4*)(&Bs[kr][c4 * 4]) =
            *(const float4*)(pw + (long)kr * DM + slab * 256 + c4 * 4);
    }
    __syncthreads();
    int colg = tid & 31;       // *8 cols
    int rowg = tid >> 5;       // *4 rows
    float acc[4][8];
#pragma unroll
    for (int r = 0; r < 4; r++)
#pragma unroll
        for (int j = 0; j < 8; j++) acc[r][j] = 0.f;

#pragma unroll
    for (int kk = 0; kk < DP; kk += 4) {
        float a_[4][4];
#pragma unroll
        for (int r = 0; r < 4; r++) {
            float4 t4 = *(const float4*)(&As[(rowg * 4 + r) * DP + kk]);
            a_[r][0] = t4.x; a_[r][1] = t4.y; a_[r][2] = t4.z; a_[r][3] = t4.w;
        }
#pragma unroll
        for (int q = 0; q < 4; q++) {
            float bv[8];
            *(float4*)&bv[0] = *(const float4*)(&Bs[kk + q][colg * 8]);
            *(float4*)&bv[4] = *(const float4*)(&Bs[kk + q][colg * 8 + 4]);
#pragma unroll
            for (int r = 0; r < 4; r++)
#pragma unroll
                for (int j = 0; j < 8; j++)
                    acc[r][j] = fmaf(a_[r][q], bv[j], acc[r][j]);
        }
    }
    int col0 = slab * 256 + colg * 8;
    float4 b0 = *(const float4*)(pb + col0);
    float4 b1 = *(const float4*)(pb + col0 + 4);
#pragma unroll
    for (int r = 0; r < 4; r++) {
        long off = ((long)bn * 64 + rowg * 4 + r) * DM + col0;
        float4 o0, o1;
        o0.x = acc[r][0] + b0.x; o0.y = acc[r][1] + b0.y;
        o0.z = acc[r][2] + b0.z; o0.w = acc[r][3] + b0.w;
        o1.x = acc[r][4] + b1.x; o1.y = acc[r][5] + b1.y;
        o1.z = acc[r][6] + b1.z; o1.w = acc[r][7] + b1.w;
        *(float4*)(acoustic + off)     = o0;
        *(float4*)(acoustic + off + 4) = o1;
    }
}

// ---------------- K5: swin_tok = gather(swin_2d) @ swin_w + swin_b ----------
// block = one (b,n) x 256-col slab; K=192 in 4 chunks of 48 staged in LDS.
__global__ __launch_bounds__(256) void swin_kernel(
    const float* __restrict__ sw2d, const float* __restrict__ sww,
    const float* __restrict__ swb, const int* __restrict__ fw,
    float* __restrict__ acoustic)
{
    __shared__ float As[H_SW * DSW];   // 32x192 = 24KB
    __shared__ float Bs[48][256];      // 48KB
    int bid = blockIdx.x;
    int slab = bid & 1;
    int bn = bid >> 1;
    int b = bn >> 7;
    int tid = threadIdx.x;
    int wcol = fw[bn];
    // stage A: gathered rows swin_2d[b, h, wcol, :]  (1536 float4, 6/thread)
#pragma unroll
    for (int i = 0; i < 6; i++) {
        int idx = tid + i * 256;
        int h = idx / 48, c4 = idx - h * 48;
        ((float4*)As)[idx] =
            *(const float4*)(sw2d + (((long)(b * H_SW + h)) * W_SW + wcol) * DSW + c4 * 4);
    }
    int colg = tid & 31;
    int rowg = tid >> 5;
    float acc[4][8];
#pragma unroll
    for (int r = 0; r < 4; r++)
#pragma unroll
        for (int j = 0; j < 8; j++) acc[r][j] = 0.f;

    for (int kc = 0; kc < 4; kc++) {
        __syncthreads();   // A visible (first iter); prev-chunk compute done (later)
        // stage B chunk: 48x256 = 3072 float4, 12/thread
#pragma unroll
        for (int i = 0; i < 12; i++) {
            int idx = tid + i * 256;
            int kr = idx >> 6, c4 = idx & 63;
            *(float4*)(&Bs[kr][c4 * 4]) =
                *(const float4*)(sww + ((long)(kc * 48 + kr)) * DM + slab * 256 + c4 * 4);
        }
        __syncthreads();
#pragma unroll
        for (int kk = 0; kk < 48; kk += 4) {
            float a_[4][4];
#pragma unroll
            for (int r = 0; r < 4; r++) {
                float4 t4 = *(const float4*)(&As[(rowg * 4 + r) * DSW + kc * 48 + kk]);
                a_[r][0] = t4.x; a_[r][1] = t4.y; a_[r][2] = t4.z; a_[r][3] = t4.w;
            }
#pragma unroll
            for (int q = 0; q < 4; q++) {
                float bv[8];
                *(float4*)&bv[0] = *(const float4*)(&Bs[kk + q][colg * 8]);
                *(float4*)&bv[4] = *(const float4*)(&Bs[kk + q][colg * 8 + 4]);
#pragma unroll
                for (int r = 0; r < 4; r++)
#pragma unroll
                    for (int j = 0; j < 8; j++)
                        acc[r][j] = fmaf(a_[r][q], bv[j], acc[r][j]);
            }
        }
    }
    int col0 = slab * 256 + colg * 8;
    float4 b0 = *(const float4*)(swb + col0);
    float4 b1 = *(const float4*)(swb + col0 + 4);
#pragma unroll
    for (int r = 0; r < 4; r++) {
        long off = ((long)bn * 64 + 32 + rowg * 4 + r) * DM + col0;
        float4 o0, o1;
        o0.x = acc[r][0] + b0.x; o0.y = acc[r][1] + b0.y;
        o0.z = acc[r][2] + b0.z; o0.w = acc[r][3] + b0.w;
        o1.x = acc[r][4] + b1.x; o1.y = acc[r][5] + b1.y;
        o1.z = acc[r][6] + b1.z; o1.w = acc[r][7] + b1.w;
        *(float4*)(acoustic + off)     = o0;
        *(float4*)(acoustic + off + 4) = o1;
    }
}

extern "C" void kernel_launch(void* const* d_in, const int* in_sizes, int n_in,
                              void* d_out, int out_size, void* d_ws, size_t ws_size,
                              hipStream_t stream)
{
    const float* fs      = (const float*)d_in[0];
    const float* swin2d  = (const float*)d_in[1];
    const float* pt      = (const float*)d_in[2];
    const int*   target  = (const int*)d_in[3];
    const float* conv_w  = (const float*)d_in[4];
    const float* ln_w    = (const float*)d_in[5];
    const float* ln_b    = (const float*)d_in[6];
    const float* dense_w = (const float*)d_in[7];
    const float* dense_b = (const float*)d_in[8];
    const float* proj_w  = (const float*)d_in[9];
    const float* proj_b  = (const float*)d_in[10];
    const float* pitch_w = (const float*)d_in[11];
    const float* pitch_b = (const float*)d_in[12];
    const float* swin_w  = (const float*)d_in[13];
    const float* swin_b  = (const float*)d_in[14];

    float* out      = (float*)d_out;
    float* acoustic = out;                                   // 16*128*64*512
    float* alpha    = out + (long)B_SZ * NF * 64 * DM;       // 48000
    float* qty      = alpha + B_SZ * T_FIRE;                 // 1

    int*   fw    = (int*)d_ws;                               // 16*128 ints
    float* qpart = (float*)((char*)d_ws + B_SZ * NF * sizeof(int));

    alpha_kernel<<<B_SZ * T_FIRE / 4, 256, 0, stream>>>(
        fs, conv_w, ln_w, ln_b, dense_w, dense_b, proj_w, proj_b, alpha);
    fires_kernel<<<B_SZ, 1024, 0, stream>>>(alpha, target, fw, qpart);
    qty_kernel<<<1, 64, 0, stream>>>(qpart, qty);
    pitch_kernel<<<B_SZ * NF * 2, 256, 0, stream>>>(pt, pitch_w, pitch_b, acoustic);
    swin_kernel<<<B_SZ * NF * 2, 256, 0, stream>>>(swin2d, swin_w, swin_b, fw, acoustic);
}

// Round 2
// 466.512 us; speedup vs baseline: 1.3915x; 1.3915x over previous
//
#include <hip/hip_runtime.h>
#include <math.h>

#define T_FIRE 3000
#define B_SZ 16
#define C_CH 32
#define HID 128
#define NF 128
#define H_SW 32
#define W_SW 375
#define DSW 192
#define DM 512
#define P_POLY 32
#define DP 32

typedef __attribute__((ext_vector_type(8))) short bf16x8;
typedef __attribute__((ext_vector_type(4))) float f32x4;

__device__ inline short f2bf(float f) {
    union { float f; unsigned u; } v; v.f = f;
    unsigned r = v.u + 0x7FFF + ((v.u >> 16) & 1);   // RNE
    return (short)(r >> 16);
}

__device__ inline bf16x8 load_afrag(const float* __restrict__ p) {
    float4 x = *(const float4*)p;
    float4 y = *(const float4*)(p + 4);
    bf16x8 f;
    f[0] = f2bf(x.x); f[1] = f2bf(x.y); f[2] = f2bf(x.z); f[3] = f2bf(x.w);
    f[4] = f2bf(y.x); f[5] = f2bf(y.y); f[6] = f2bf(y.z); f[7] = f2bf(y.w);
    return f;
}

// ---------------- K1: alpha = softplus(proj(relu(dense(LN(conv+res))))) ----
__global__ __launch_bounds__(256) void alpha_kernel(
    const float* __restrict__ fs, const float* __restrict__ conv_w,
    const float* __restrict__ ln_w, const float* __restrict__ ln_b,
    const float* __restrict__ dense_w, const float* __restrict__ dense_b,
    const float* __restrict__ proj_w, const float* __restrict__ proj_b,
    float* __restrict__ alpha_out)
{
    int lane = threadIdx.x & 63;
    int wave = threadIdx.x >> 6;
    int r = blockIdx.x * 4 + wave;
    int b = r / T_FIRE, t = r - b * T_FIRE;
    int c = lane & 31;
    long base = ((long)(b * T_FIRE + t)) * C_CH + c;
    float xc = fs[base];
    float xm = (t > 0)          ? fs[base - C_CH] : 0.f;
    float xp = (t < T_FIRE - 1) ? fs[base + C_CH] : 0.f;
    float w0 = conv_w[c * 3 + 0], w1 = conv_w[c * 3 + 1], w2 = conv_w[c * 3 + 2];
    float x = xc + xm * w0 + xc * w1 + xp * w2;
    float s = x, s2 = x * x;
#pragma unroll
    for (int o = 1; o < 64; o <<= 1) { s += __shfl_xor(s, o); s2 += __shfl_xor(s2, o); }
    float mean = s * (1.f / 64.f);
    float var  = s2 * (1.f / 64.f) - mean * mean;
    float xn = (x - mean) * rsqrtf(var + 1e-5f) * ln_w[c] + ln_b[c];
    float a0 = dense_b[lane], a1 = dense_b[lane + 64];
#pragma unroll
    for (int cc = 0; cc < 32; cc++) {
        float xv = __shfl(xn, cc);
        a0 = fmaf(xv, dense_w[cc * HID + lane], a0);
        a1 = fmaf(xv, dense_w[cc * HID + lane + 64], a1);
    }
    a0 = fmaxf(a0, 0.f);
    a1 = fmaxf(a1, 0.f);
    float v = a0 * proj_w[lane] + a1 * proj_w[lane + 64];
#pragma unroll
    for (int o = 1; o < 64; o <<= 1) v += __shfl_xor(v, o);
    if (lane == 0) {
        float z = v + proj_b[0];
        alpha_out[r] = fmaxf(z, 0.f) + log1pf(expf(-fabsf(z)));
    }
}

// ---------------- K2: fires scan + qty partials -----------------------------
__global__ __launch_bounds__(1024) void fires_kernel(
    const float* __restrict__ alpha, const int* __restrict__ target,
    int* __restrict__ fw, float* __restrict__ qpart)
{
    __shared__ int wtot[16];
    __shared__ int sbase;
    __shared__ float ssig[16];
    int b = blockIdx.x, tid = threadIdx.x;
    int lane = tid & 63, w = tid >> 6;
    if (tid < NF) fw[b * NF + tid] = (T_FIRE - 1) >> 3;   // 374 = padded slots
    if (tid == 0) sbase = 0;
    float psig = 0.f;
    __syncthreads();
    for (int chunk = 0; chunk < 3; chunk++) {
        int idx = chunk * 1024 + tid;
        bool valid = idx < T_FIRE;
        float a = valid ? alpha[b * T_FIRE + idx] : 0.f;
        if (valid) psig += 1.f / (1.f + expf(-(a - 1.0f) * 10.f));
        bool flag = valid && (a > 1.0f);
        unsigned long long mask = __ballot(flag);
        int prefix = __popcll(mask & ((1ull << lane) - 1ull));
        if (lane == 0) wtot[w] = __popcll(mask);
        __syncthreads();
        if (tid == 0) {
            int run = sbase;
            for (int i = 0; i < 16; i++) { int v2 = wtot[i]; wtot[i] = run; run += v2; }
            sbase = run;
        }
        __syncthreads();
        int rank = wtot[w] + prefix;
        if (flag && rank < NF) fw[b * NF + rank] = idx >> 3;
        __syncthreads();
    }
#pragma unroll
    for (int o = 1; o < 64; o <<= 1) psig += __shfl_xor(psig, o);
    if (lane == 0) ssig[w] = psig;
    __syncthreads();
    if (tid == 0) {
        float tot = 0.f;
        for (int i = 0; i < 16; i++) tot += ssig[i];
        qpart[b] = fabsf(tot - (float)target[b]);
    }
}

// ---------------- K3: qty_loss = mean(qpart) --------------------------------
__global__ void qty_kernel(const float* __restrict__ qpart, float* __restrict__ out)
{
    int lane = threadIdx.x;
    float v = (lane < B_SZ) ? qpart[lane] : 0.f;
#pragma unroll
    for (int o = 1; o < 64; o <<= 1) v += __shfl_xor(v, o);
    if (lane == 0) out[0] = v * (1.f / B_SZ);
}

// ---------------- K4: pack weights to bf16 in B-fragment order --------------
// Bpack[ks][ct][lane][j] = W[ks*32 + (lane>>4)*8 + j][ct*16 + (lane&15)]
// swin: ks<6 (12288 lane-tasks), pitch: ks==0 only (2048 lane-tasks)
__global__ __launch_bounds__(256) void pack_kernel(
    const float* __restrict__ pw, const float* __restrict__ sww,
    short* __restrict__ bp_p, short* __restrict__ bp_s)
{
    int t = blockIdx.x * 256 + threadIdx.x;
    if (t < 12288) {
        int lane = t & 63;
        int ct = (t >> 6) & 31;
        int ks = t >> 11;
        int k0 = ks * 32 + (lane >> 4) * 8;
        int n  = ct * 16 + (lane & 15);
        bf16x8 v;
#pragma unroll
        for (int j = 0; j < 8; j++) v[j] = f2bf(sww[(k0 + j) * DM + n]);
        *(bf16x8*)(bp_s + (long)t * 8) = v;
    } else if (t < 14336) {
        int u = t - 12288;
        int lane = u & 63;
        int ct = u >> 6;
        int k0 = (lane >> 4) * 8;
        int n  = ct * 16 + (lane & 15);
        bf16x8 v;
#pragma unroll
        for (int j = 0; j < 8; j++) v[j] = f2bf(pw[(k0 + j) * DM + n]);
        *(bf16x8*)(bp_p + (long)u * 8) = v;
    }
}

// ---------------- K5: fused acoustic tokens (pitch + swin) via MFMA ---------
// block = one (b,n): 64 rows x 512 cols. 8 waves:
//   sec = w>>2 (0 pitch rows 0-31 | 1 swin rows 32-63), band=(w>>1)&1, ch=w&1.
// Each wave: 16 accum tiles 16x16 (64 VGPR), A-frags from global fp32
// (converted in-reg), B-frags from packed bf16 (coalesced 16B/lane). No LDS.
__global__ __launch_bounds__(512) void tok_kernel(
    const float* __restrict__ pt, const float* __restrict__ sw2d,
    const short* __restrict__ bp_p, const short* __restrict__ bp_s,
    const float* __restrict__ pb, const float* __restrict__ swb,
    const int* __restrict__ fw, float* __restrict__ acoustic)
{
    int bn = blockIdx.x;                 // 0..2047
    int b  = bn >> 7;
    int w    = threadIdx.x >> 6;         // 0..7
    int lane = threadIdx.x & 63;
    int quad = lane >> 4, m16 = lane & 15;
    int sec  = w >> 2;
    int band = (w >> 1) & 1;
    int ch   = w & 1;

    f32x4 acc[16];
#pragma unroll
    for (int i = 0; i < 16; i++) acc[i] = (f32x4){0.f, 0.f, 0.f, 0.f};

    if (sec == 0) {
        // pitch: A = pitch_tokens[b,n] 32x32, K=32 -> one k-step
        const float* arow = pt + ((long)bn * 32 + band * 16 + m16) * DP + quad * 8;
        bf16x8 af = load_afrag(arow);
        const bf16x8* bpp = (const bf16x8*)bp_p;
#pragma unroll
        for (int ct = 0; ct < 16; ct++) {
            bf16x8 bf_ = bpp[(long)(ch * 16 + ct) * 64 + lane];
            acc[ct] = __builtin_amdgcn_mfma_f32_16x16x32_bf16(af, bf_, acc[ct], 0, 0, 0);
        }
    } else {
        // swin: A row m = swin_2d[b, band*16+m16, wcol, :], K=192 -> 6 k-steps
        int wcol = fw[bn];
        const float* arow =
            sw2d + (((long)(b * H_SW + band * 16 + m16)) * W_SW + wcol) * DSW + quad * 8;
        const bf16x8* bps = (const bf16x8*)bp_s;
#pragma unroll 1
        for (int ks = 0; ks < 6; ks++) {
            bf16x8 af = load_afrag(arow + ks * 32);
#pragma unroll
            for (int ct = 0; ct < 16; ct++) {
                bf16x8 bf_ = bps[(long)(ks * 32 + ch * 16 + ct) * 64 + lane];
                acc[ct] = __builtin_amdgcn_mfma_f32_16x16x32_bf16(af, bf_, acc[ct], 0, 0, 0);
            }
        }
    }

    // epilogue: C/D layout col = lane&15, row = quad*4 + r
    const float* bias = (sec == 0) ? pb : swb;
    long rowbase = ((long)bn * 64 + sec * 32 + band * 16 + quad * 4) * DM;
#pragma unroll
    for (int ct = 0; ct < 16; ct++) {
        int col = ch * 256 + ct * 16 + m16;
        float bv = bias[col];
#pragma unroll
        for (int r = 0; r < 4; r++)
            acoustic[rowbase + (long)r * DM + col] = acc[ct][r] + bv;
    }
}

extern "C" void kernel_launch(void* const* d_in, const int* in_sizes, int n_in,
                              void* d_out, int out_size, void* d_ws, size_t ws_size,
                              hipStream_t stream)
{
    const float* fs      = (const float*)d_in[0];
    const float* swin2d  = (const float*)d_in[1];
    const float* pt      = (const float*)d_in[2];
    const int*   target  = (const int*)d_in[3];
    const float* conv_w  = (const float*)d_in[4];
    const float* ln_w    = (const float*)d_in[5];
    const float* ln_b    = (const float*)d_in[6];
    const float* dense_w = (const float*)d_in[7];
    const float* dense_b = (const float*)d_in[8];
    const float* proj_w  = (const float*)d_in[9];
    const float* proj_b  = (const float*)d_in[10];
    const float* pitch_w = (const float*)d_in[11];
    const float* pitch_b = (const float*)d_in[12];
    const float* swin_w  = (const float*)d_in[13];
    const float* swin_b  = (const float*)d_in[14];

    float* out      = (float*)d_out;
    float* acoustic = out;                                   // 16*128*64*512
    float* alpha    = out + (long)B_SZ * NF * 64 * DM;       // 48000
    float* qty      = alpha + B_SZ * T_FIRE;                 // 1

    char* ws = (char*)d_ws;
    int*   fw    = (int*)ws;                                  ws += B_SZ * NF * sizeof(int);
    float* qpart = (float*)ws;                                ws += 64 * sizeof(float);
    short* bp_s  = (short*)ws;                                ws += (long)DSW * DM * sizeof(short);
    short* bp_p  = (short*)ws;                                ws += (long)DP * DM * sizeof(short);

    alpha_kernel<<<B_SZ * T_FIRE / 4, 256, 0, stream>>>(
        fs, conv_w, ln_w, ln_b, dense_w, dense_b, proj_w, proj_b, alpha);
    pack_kernel<<<56, 256, 0, stream>>>(pitch_w, swin_w, bp_p, bp_s);
    fires_kernel<<<B_SZ, 1024, 0, stream>>>(alpha, target, fw, qpart);
    qty_kernel<<<1, 64, 0, stream>>>(qpart, qty);
    tok_kernel<<<B_SZ * NF, 512, 0, stream>>>(
        pt, swin2d, bp_p, bp_s, pitch_b, swin_b, fw, acoustic);
}